// Round 9
// baseline (83.308 us; speedup 1.0000x reference)
//
#include <hip/hip_runtime.h>

// B=256, IN_F=512, K_INT=75 (pad 80), OUT_F=64
// ws: Tb2[o][k_pad80][f] bf16 @ 0         (64*80*512*2 = 5,242,880 B)
//     xb[b][f]           bf16 @ 5,242,880 (256*512*2   =   262,144 B)

typedef __attribute__((ext_vector_type(8))) short bf16x8;
typedef __attribute__((ext_vector_type(4))) float f32x4;
typedef unsigned short u16;
typedef unsigned int u32;

__device__ inline u16 f2bf(float f) {            // RNE float->bf16 bits
  u32 u = __float_as_uint(f);
  return (u16)((u + 0x7FFFu + ((u >> 16) & 1u)) >> 16);
}

// ---------- fused convert ----------
// bid < 640: T[f][k][o] -> Tb2[o][k][f] tiles (k = bid>>3 in 0..79, rows k>=75 zeroed)
// bid >= 640: x[256][512] -> xb bf16
__global__ __launch_bounds__(256) void cvt_all(const float* __restrict__ x,
                                               const float* __restrict__ T,
                                               u16* __restrict__ xb,
                                               u16* __restrict__ Tb2) {
  const int bid = blockIdx.x;
  const int tid = threadIdx.x;

  if (bid >= 640) {                  // ---- x convert: 64 blocks x 256 thr x 8 elems
    const int i = (bid - 640) * 256 + tid;
    const float4* x4 = reinterpret_cast<const float4*>(x);
    const float4 v0 = x4[i * 2], v1 = x4[i * 2 + 1];
    uint4 o;
    o.x = (u32)f2bf(v0.x) | ((u32)f2bf(v0.y) << 16);
    o.y = (u32)f2bf(v0.z) | ((u32)f2bf(v0.w) << 16);
    o.z = (u32)f2bf(v1.x) | ((u32)f2bf(v1.y) << 16);
    o.w = (u32)f2bf(v1.z) | ((u32)f2bf(v1.w) << 16);
    *reinterpret_cast<uint4*>(xb + i * 8) = o;
    return;
  }

  // ---- T-transpose tile: f-chunk 64 x one k, all 64 o
  const int f0 = (bid & 7) << 6;
  const int k = bid >> 3;            // 0..79
  const int w = tid >> 2;            // o row 0..63
  const int c = tid & 3;             // 16-col group
  u16* dst = Tb2 + (w * 80 + k) * 512 + f0 + (c << 4);

  if (k >= 75) {                     // zero-fill pad rows (keeps MFMA clean)
    const uint4 z = make_uint4(0, 0, 0, 0);
    reinterpret_cast<uint4*>(dst)[0] = z;
    reinterpret_cast<uint4*>(dst)[1] = z;
    return;
  }

  __shared__ float tile[64][65];     // [f_local][o], pad 65
  const float4* T4 = reinterpret_cast<const float4*>(T);
#pragma unroll
  for (int h = 0; h < 4; ++h) {
    const int q = c + (h << 2);                        // o-quad 0..15
    const float4 v = T4[(f0 + (tid >> 2)) * 1200 + k * 16 + q];
    tile[tid >> 2][(q << 2) + 0] = v.x;
    tile[tid >> 2][(q << 2) + 1] = v.y;
    tile[tid >> 2][(q << 2) + 2] = v.z;
    tile[tid >> 2][(q << 2) + 3] = v.w;
  }
  __syncthreads();

  u16 us[16];
#pragma unroll
  for (int j = 0; j < 16; ++j) us[j] = f2bf(tile[(c << 4) + j][w]);
  uint4 p0, p1;
  p0.x = (u32)us[0] | ((u32)us[1] << 16);
  p0.y = (u32)us[2] | ((u32)us[3] << 16);
  p0.z = (u32)us[4] | ((u32)us[5] << 16);
  p0.w = (u32)us[6] | ((u32)us[7] << 16);
  p1.x = (u32)us[8] | ((u32)us[9] << 16);
  p1.y = (u32)us[10] | ((u32)us[11] << 16);
  p1.z = (u32)us[12] | ((u32)us[13] << 16);
  p1.w = (u32)us[14] | ((u32)us[15] << 16);
  reinterpret_cast<uint4*>(dst)[0] = p0;
  reinterpret_cast<uint4*>(dst)[1] = p1;
}

// ---------- fused MFMA + pairwise ----------
// Grid 256 (o = bid&63, itile = bid>>6 -> same-o blocks on same XCD), 512 thr, 1 block/CU.
// Phase A: Ms[k][b] = sum_f Tb2[o][k][f]*xb[b][f] via MFMA, wave w owns b=[32w,32w+32).
// Phase B: thread (il,jg) = 2 i's x 16 j's; j-reads are wave-broadcast float4s.
#define MSTR 260   // fp32 row stride (1040 B): 16B-aligned, 2-way-free D-stores
__global__ __launch_bounds__(512) void md_fused(const u16* __restrict__ Tb2,
                                                const u16* __restrict__ xb,
                                                float* __restrict__ out) {
  const int bid = blockIdx.x;
  const int o = bid & 63;
  const int it = bid >> 6;           // i-tile 0..3
  const int tid = threadIdx.x;

  __shared__ float Ms[80 * MSTR];    // 83,200 B

  // ---- phase A: MFMA straight into LDS
  {
    const int w = tid >> 6, l = tid & 63;
    const int b0 = w << 5;           // 32 b per wave
    const int lr = l & 15;
    const int ko = (l >> 4) << 3;    // 8 contiguous k-elems
    const u16* Ab = Tb2 + o * (80 * 512);
    const u16* B0 = xb + (b0 + lr) * 512 + ko;
    const u16* B1 = B0 + 16 * 512;
#pragma unroll
    for (int kt = 0; kt < 5; ++kt) {
      const u16* Ak = Ab + (kt * 16 + lr) * 512 + ko;
      f32x4 d0 = {0.f, 0.f, 0.f, 0.f}, d1 = d0;
#pragma unroll 4
      for (int ks = 0; ks < 16; ++ks) {
        const bf16x8 a  = *reinterpret_cast<const bf16x8*>(Ak + (ks << 5));
        const bf16x8 f0 = *reinterpret_cast<const bf16x8*>(B0 + (ks << 5));
        const bf16x8 f1 = *reinterpret_cast<const bf16x8*>(B1 + (ks << 5));
        d0 = __builtin_amdgcn_mfma_f32_16x16x32_bf16(a, f0, d0, 0, 0, 0);
        d1 = __builtin_amdgcn_mfma_f32_16x16x32_bf16(a, f1, d1, 0, 0, 0);
      }
      // D: col(=b)=lane&15, row(=k)=(lane>>4)*4+r  [m89-verified, validated R5-R8]
#pragma unroll
      for (int r = 0; r < 4; ++r) {
        const int krow = kt * 16 + ((l >> 4) << 2) + r;
        Ms[krow * MSTR + b0 + lr] = d0[r];
        Ms[krow * MSTR + b0 + 16 + lr] = d1[r];
      }
    }
  }
  __syncthreads();

  // ---- phase B: pairwise L1 + exp + partial row-sum
  const int il = tid & 31;           // i-pair slot: i_local = 2*il (+e)
  const int jg = tid >> 5;           // 0..15 -> j in [16*jg, 16*jg+16)
  const int ci = (it << 6) + (il << 1);   // global column of own i-pair

  float dd0[16], dd1[16];
#pragma unroll
  for (int q = 0; q < 16; ++q) { dd0[q] = 0.0f; dd1[q] = 0.0f; }

  for (int k = 0; k < 75; ++k) {
    const float* row = Ms + k * MSTR;
    const float miA = row[ci];                         // 32 addrs, 2-way: free
    const float miB = row[ci + 1];
    const float4* jr = reinterpret_cast<const float4*>(row + (jg << 4));
#pragma unroll
    for (int q = 0; q < 4; ++q) {
      const float4 v = jr[q];                          // 2 distinct addrs/wave: broadcast
      dd0[4 * q + 0] += __builtin_fabsf(v.x - miA);
      dd0[4 * q + 1] += __builtin_fabsf(v.y - miA);
      dd0[4 * q + 2] += __builtin_fabsf(v.z - miA);
      dd0[4 * q + 3] += __builtin_fabsf(v.w - miA);
      dd1[4 * q + 0] += __builtin_fabsf(v.x - miB);
      dd1[4 * q + 1] += __builtin_fabsf(v.y - miB);
      dd1[4 * q + 2] += __builtin_fabsf(v.z - miB);
      dd1[4 * q + 3] += __builtin_fabsf(v.w - miB);
    }
  }

  float sA = 0.0f, sB = 0.0f;
#pragma unroll
  for (int q = 0; q < 16; ++q) {
    sA += __expf(-dd0[q]);           // j==i term exp(0)=1, cancelled by -1 below
    sB += __expf(-dd1[q]);
  }

  __syncthreads();                   // Ms reads done; overlay reduce scratch
  float* red = Ms;                   // red[i_local][jg], stride 17: conflict-free
  red[((il << 1) + 0) * 17 + jg] = sA;
  red[((il << 1) + 1) * 17 + jg] = sB;
  __syncthreads();
  if (tid < 64) {
    float s = 0.0f;
#pragma unroll
    for (int g = 0; g < 16; ++g) s += red[tid * 17 + g];
    out[((it << 6) + tid) * 64 + o] = s - 1.0f;
  }
}

extern "C" void kernel_launch(void* const* d_in, const int* in_sizes, int n_in,
                              void* d_out, int out_size, void* d_ws, size_t ws_size,
                              hipStream_t stream) {
  const float* x = (const float*)d_in[0];   // [256,512]
  const float* T = (const float*)d_in[1];   // [512,75,64]
  float* out = (float*)d_out;               // [256,64]

  char* ws = (char*)d_ws;
  u16* Tb2 = (u16*)ws;                      // 5,242,880 B
  u16* xb = (u16*)(ws + 5242880);           //   262,144 B

  cvt_all<<<704, 256, 0, stream>>>(x, T, xb, Tb2);
  md_fused<<<256, 512, 0, stream>>>(Tb2, xb, out);
}

// Round 11
// 56.014 us; speedup vs baseline: 1.4873x; 1.4873x over previous
//
#include <hip/hip_runtime.h>

// B=256, IN_F=512, K_INT=75, OUT_F=64
// ws: Mt2[z][o][k][b] fp32 @ 0          (2 x 4,915,200 B) — K-split slabs
//     Tb[k*64+o][f] bf16   @ 9,830,400  (4,915,200 B)
//     xb[b][f] bf16        @ 14,745,600 (  262,144 B)

typedef __attribute__((ext_vector_type(8))) short bf16x8;
typedef __attribute__((ext_vector_type(4))) float f32x4;
typedef unsigned short u16;
typedef unsigned int u32;

__device__ inline u16 f2bf(float f) {            // RNE float->bf16 bits
  u32 u = __float_as_uint(f);
  return (u16)((u + 0x7FFFu + ((u >> 16) & 1u)) >> 16);
}
__device__ inline float bflo(u32 u) { return __uint_as_float(u << 16); }
__device__ inline float bfhi(u32 u) { return __uint_as_float(u & 0xFFFF0000u); }

// ---------- fused convert (verbatim R8): bid<600 T-tiles, >=600 x-chunks ----------
__global__ __launch_bounds__(256) void cvt_all(const float* __restrict__ x,
                                               const float* __restrict__ T,
                                               u16* __restrict__ xb,
                                               u16* __restrict__ Tb) {
  const int bid = blockIdx.x;
  const int tid = threadIdx.x;

  if (bid >= 600) {
    const int i = (bid - 600) * 256 + tid;
    const float4* x4 = reinterpret_cast<const float4*>(x);
    const float4 v0 = x4[i * 2], v1 = x4[i * 2 + 1];
    uint4 o;
    o.x = (u32)f2bf(v0.x) | ((u32)f2bf(v0.y) << 16);
    o.y = (u32)f2bf(v0.z) | ((u32)f2bf(v0.w) << 16);
    o.z = (u32)f2bf(v1.x) | ((u32)f2bf(v1.y) << 16);
    o.w = (u32)f2bf(v1.z) | ((u32)f2bf(v1.w) << 16);
    *reinterpret_cast<uint4*>(xb + i * 8) = o;
    return;
  }

  const int f0 = (bid & 7) << 6;
  const int k = bid >> 3;            // 0..74
  __shared__ float tile[64][65];

  const float4* T4 = reinterpret_cast<const float4*>(T);
  const int r = tid >> 2;
  const int c = tid & 3;
#pragma unroll
  for (int h = 0; h < 4; ++h) {
    const int q = c + (h << 2);
    const float4 v = T4[(f0 + r) * 1200 + k * 16 + q];
    tile[r][(q << 2) + 0] = v.x;
    tile[r][(q << 2) + 1] = v.y;
    tile[r][(q << 2) + 2] = v.z;
    tile[r][(q << 2) + 3] = v.w;
  }
  __syncthreads();

  const int w = tid >> 2;
  u16 us[16];
#pragma unroll
  for (int j = 0; j < 16; ++j) us[j] = f2bf(tile[(c << 4) + j][w]);
  uint4 p0, p1;
  p0.x = (u32)us[0] | ((u32)us[1] << 16);
  p0.y = (u32)us[2] | ((u32)us[3] << 16);
  p0.z = (u32)us[4] | ((u32)us[5] << 16);
  p0.w = (u32)us[6] | ((u32)us[7] << 16);
  p1.x = (u32)us[8] | ((u32)us[9] << 16);
  p1.y = (u32)us[10] | ((u32)us[11] << 16);
  p1.z = (u32)us[12] | ((u32)us[13] << 16);
  p1.w = (u32)us[14] | ((u32)us[15] << 16);
  uint4* dst = reinterpret_cast<uint4*>(Tb + ((k << 6) + w) * 512 + f0 + (c << 4));
  dst[0] = p0;
  dst[1] = p1;
}

// ---------- MFMA GEMM, K-split x2 (R5 structure, halved K per block) ----------
__global__ __launch_bounds__(256) void md_gemm_mfma(const u16* __restrict__ Tb,
                                                    const u16* __restrict__ xb,
                                                    float* __restrict__ Mt2) {
  const int tid = threadIdx.x;
  const int l = tid & 63, w = tid >> 6;
  const int n0 = (blockIdx.x << 6) + ((w >> 1) << 5);
  const int b0 = (blockIdx.y << 6) + ((w & 1) << 5);
  const int z = blockIdx.z;          // K-half: f in [z*256, z*256+256)
  const int lr = l & 15;
  const int ko = (l >> 4) << 3;

  const u16* pa0 = Tb + (n0 + lr) * 512 + z * 256 + ko;
  const u16* pa1 = pa0 + 16 * 512;
  const u16* pb0 = xb + (b0 + lr) * 512 + z * 256 + ko;
  const u16* pb1 = pb0 + 16 * 512;

  f32x4 d00 = {0.f, 0.f, 0.f, 0.f}, d01 = d00, d10 = d00, d11 = d00;

#pragma unroll 4
  for (int kk = 0; kk < 8; ++kk) {
    const int off = kk << 5;
    const bf16x8 a0 = *reinterpret_cast<const bf16x8*>(pa0 + off);
    const bf16x8 a1 = *reinterpret_cast<const bf16x8*>(pa1 + off);
    const bf16x8 f0 = *reinterpret_cast<const bf16x8*>(pb0 + off);
    const bf16x8 f1 = *reinterpret_cast<const bf16x8*>(pb1 + off);
    d00 = __builtin_amdgcn_mfma_f32_16x16x32_bf16(a0, f0, d00, 0, 0, 0);
    d01 = __builtin_amdgcn_mfma_f32_16x16x32_bf16(a0, f1, d01, 0, 0, 0);
    d10 = __builtin_amdgcn_mfma_f32_16x16x32_bf16(a1, f0, d10, 0, 0, 0);
    d11 = __builtin_amdgcn_mfma_f32_16x16x32_bf16(a1, f1, d11, 0, 0, 0);
  }

  float* Mt = Mt2 + z * 1228800;     // slab
#pragma unroll
  for (int r = 0; r < 4; ++r) {
    const int row = ((l >> 4) << 2) + r;
    {
      const int n = n0 + row;
      float* base = Mt + (n & 63) * 19200 + (n >> 6) * 256;
      base[b0 + lr] = d00[r];
      base[b0 + 16 + lr] = d01[r];
    }
    {
      const int n = n0 + 16 + row;
      float* base = Mt + (n & 63) * 19200 + (n >> 6) * 256;
      base[b0 + lr] = d10[r];
      base[b0 + 16 + lr] = d11[r];
    }
  }
}

// ---------- pairwise: 4i x 8j threads, bf16 j-panel, f32 i-panel, k-halved ----------
// Self-term is SKIPPED in-register (not cancelled by -1): mixed-precision panels safe.
__global__ __launch_bounds__(256) void md_pair3(const float* __restrict__ Mt2,
                                                float* __restrict__ out) {
  const int bid = blockIdx.x;
  const int o = bid & 63;
  const int it = bid >> 6;             // 0..7
  const int ibase = it << 5;           // 32 i per block
  const int tid = threadIdx.x;
  const int is = tid & 7;              // i = ibase + 4*is + a
  const int jg = tid >> 3;             // j = 8*jg + b

  __shared__ alignas(16) u16 MjB[38 * 256];    // 19,456 B  bf16 j-panel
  __shared__ alignas(16) float MiF[38 * 32];   //  4,864 B  f32 i-panel

  const float* M0 = Mt2 + o * 19200;           // slab 0
  const float* M1 = M0 + 1228800;              // slab 1

  float d[4][8];
#pragma unroll
  for (int a = 0; a < 4; ++a)
#pragma unroll
    for (int b = 0; b < 8; ++b) d[a][b] = 0.0f;

  for (int h = 0; h < 2; ++h) {
    const int kbase = h * 38;
    const int nk = h ? 37 : 38;
    __syncthreads();                   // prior reads done before overwrite
    // stage Mj (bf16 of slab0+slab1): 38 rows x 64 quad-groups
    for (int idx = tid; idx < nk * 64; idx += 256) {
      const int kk = idx >> 6, q = idx & 63;
      const int goff = (kbase + kk) * 256 + (q << 2);
      const float4 v0 = *reinterpret_cast<const float4*>(M0 + goff);
      const float4 v1 = *reinterpret_cast<const float4*>(M1 + goff);
      uint2 p;
      p.x = (u32)f2bf(v0.x + v1.x) | ((u32)f2bf(v0.y + v1.y) << 16);
      p.y = (u32)f2bf(v0.z + v1.z) | ((u32)f2bf(v0.w + v1.w) << 16);
      *reinterpret_cast<uint2*>(MjB + kk * 256 + (q << 2)) = p;
    }
    // stage Mi (f32): 38 rows x 32
    for (int idx = tid; idx < nk * 32; idx += 256) {
      const int kk = idx >> 5, ii = idx & 31;
      const int goff = (kbase + kk) * 256 + ibase + ii;
      MiF[kk * 32 + ii] = M0[goff] + M1[goff];
    }
    __syncthreads();

    for (int kk = 0; kk < nk; ++kk) {
      const float4 vi = *reinterpret_cast<const float4*>(MiF + kk * 32 + (is << 2));
      const uint4 ju = *reinterpret_cast<const uint4*>(MjB + kk * 256 + (jg << 3));
      const float ia[4] = {vi.x, vi.y, vi.z, vi.w};
      const float ja[8] = {bflo(ju.x), bfhi(ju.x), bflo(ju.y), bfhi(ju.y),
                           bflo(ju.z), bfhi(ju.z), bflo(ju.w), bfhi(ju.w)};
#pragma unroll
      for (int a = 0; a < 4; ++a)
#pragma unroll
        for (int b = 0; b < 8; ++b) d[a][b] += __builtin_fabsf(ja[b] - ia[a]);
    }
  }

  float s[4];
#pragma unroll
  for (int a = 0; a < 4; ++a) {
    const int ia = ibase + (is << 2) + a;      // this thread's global i for slot a
    float t = 0.0f;
#pragma unroll
    for (int b = 0; b < 8; ++b) {
      const int j = (jg << 3) + b;
      const float e = __expf(-d[a][b]);
      t += (j == ia) ? 0.0f : e;               // skip self-term exactly
    }
    s[a] = t;
  }

  __syncthreads();                     // panel reads done; overlay reduce scratch
  float* red = reinterpret_cast<float*>(MjB);  // red[i_local 32][jg 32], stride 33
#pragma unroll
  for (int a = 0; a < 4; ++a) red[((is << 2) + a) * 33 + jg] = s[a];
  __syncthreads();
  if (tid < 32) {
    float t = 0.0f;
#pragma unroll
    for (int g = 0; g < 32; ++g) t += red[tid * 33 + g];
    out[(ibase + tid) * 64 + o] = t;           // self-term already excluded
  }
}

extern "C" void kernel_launch(void* const* d_in, const int* in_sizes, int n_in,
                              void* d_out, int out_size, void* d_ws, size_t ws_size,
                              hipStream_t stream) {
  const float* x = (const float*)d_in[0];   // [256,512]
  const float* T = (const float*)d_in[1];   // [512,75,64]
  float* out = (float*)d_out;               // [256,64]

  char* ws = (char*)d_ws;
  float* Mt2 = (float*)ws;                  // 2 x 4,915,200 B
  u16* Tb = (u16*)(ws + 9830400);           // 4,915,200 B
  u16* xb = (u16*)(ws + 14745600);          //   262,144 B

  cvt_all<<<664, 256, 0, stream>>>(x, T, xb, Tb);
  md_gemm_mfma<<<dim3(75, 4, 2), 256, 0, stream>>>(Tb, xb, Mt2);
  md_pair3<<<512, 256, 0, stream>>>(Mt2, out);
}